// Round 1
// baseline (260.664 us; speedup 1.0000x reference)
//
#include <hip/hip_runtime.h>

#define NT 512
#define NBOX 4096
#define MAXDET 100

// One workgroup per image. Phases:
//  1) build sort keys (score bits | inverted index) + count valid M
//  2) in-LDS bitonic sort, descending (matches stable argsort incl. ties)
//  3) greedy NMS with early exit at 100 kept (suppression parallel over j)
//  4) write packed [MAXDET,5] + num (as float)
__global__ __launch_bounds__(NT) void postproc_kernel(
    const float* __restrict__ boxes,   // [B, NBOX, 4] cxcywh
    const float* __restrict__ scores,  // [B, NBOX]
    float* __restrict__ out,           // [B*MAXDET*5] packed, then [B] num
    int B) {
  const int b = blockIdx.x;
  const int tid = threadIdx.x;

  __shared__ unsigned long long skey[NBOX];       // 32 KB: (score_bits<<32)|(4095-n)
  __shared__ unsigned long long ssup[NBOX / 64];  // suppression bitmask
  __shared__ int skept[MAXDET];
  __shared__ int s_nk, s_stop, s_M;

  const float* sc = scores + (size_t)b * NBOX;
  const float4* bx = (const float4*)boxes + (size_t)b * NBOX;

  if (tid == 0) { s_nk = 0; s_stop = 0; s_M = 0; }
  for (int i = tid; i < NBOX / 64; i += NT) ssup[i] = 0ULL;
  __syncthreads();

  // ---- Phase 1: keys + valid count ----
  int cnt = 0;
  for (int n = tid; n < NBOX; n += NT) {
    float s = sc[n];
    unsigned long long key = (unsigned long long)(unsigned int)(NBOX - 1 - n);
    if (s > 0.5f) {  // valid: positive float bits sort monotonically
      key |= ((unsigned long long)__float_as_uint(s)) << 32;
      ++cnt;
    }
    skey[n] = key;
  }
  atomicAdd(&s_M, cnt);
  __syncthreads();
  const int M = s_M;  // sorted positions [0,M) are the valid boxes

  // ---- Phase 2: bitonic sort, descending ----
  for (int k = 2; k <= NBOX; k <<= 1) {
    for (int j = k >> 1; j > 0; j >>= 1) {
      for (int t = tid; t < NBOX; t += NT) {
        int ixj = t ^ j;
        if (ixj > t) {
          unsigned long long a = skey[t], c = skey[ixj];
          bool up = (t & k) != 0;  // overall descending
          if (up ? (a > c) : (a < c)) { skey[t] = c; skey[ixj] = a; }
        }
      }
      __syncthreads();
    }
  }

  // ---- Phase 3: greedy NMS, early exit at MAXDET kept ----
  for (int i = 0; i < M; ++i) {
    bool sup_i = (ssup[i >> 6] >> (i & 63)) & 1ULL;  // uniform across threads
    if (!sup_i) {
      int oi = NBOX - 1 - (int)(skey[i] & 0xFFFFFFFFULL);
      float4 bbi = bx[oi];
      float ix1 = bbi.x - 0.5f * bbi.z, iy1 = bbi.y - 0.5f * bbi.w;
      float ix2 = bbi.x + 0.5f * bbi.z, iy2 = bbi.y + 0.5f * bbi.w;
      float ai = fmaxf(ix2 - ix1, 0.f) * fmaxf(iy2 - iy1, 0.f);
      for (int j = i + 1 + tid; j < M; j += NT) {
        int oj = NBOX - 1 - (int)(skey[j] & 0xFFFFFFFFULL);
        float4 bbj = bx[oj];
        float jx1 = bbj.x - 0.5f * bbj.z, jy1 = bbj.y - 0.5f * bbj.w;
        float jx2 = bbj.x + 0.5f * bbj.z, jy2 = bbj.y + 0.5f * bbj.w;
        float w = fmaxf(fminf(ix2, jx2) - fmaxf(ix1, jx1), 0.f);
        float h = fmaxf(fminf(iy2, jy2) - fmaxf(iy1, jy1), 0.f);
        float inter = w * h;
        float aj = fmaxf(jx2 - jx1, 0.f) * fmaxf(jy2 - jy1, 0.f);
        float iou = inter / fmaxf(ai + aj - inter, 1e-9f);
        if (iou > 0.7f) atomicOr(&ssup[j >> 6], 1ULL << (j & 63));
      }
      __syncthreads();
      if (tid == 0) {
        skept[s_nk++] = i;
        if (s_nk >= MAXDET) s_stop = 1;
      }
      __syncthreads();
      if (s_stop) break;  // num = 100; later boxes can't appear in output
    }
  }
  __syncthreads();

  // ---- Phase 4: outputs ----
  const int nk = s_nk;
  if (tid < MAXDET) {
    float v0 = 0.f, v1 = 0.f, v2 = 0.f, v3 = 0.f, v4 = 0.f;
    if (tid < nk) {
      int i = skept[tid];
      unsigned long long key = skey[i];
      int orig = NBOX - 1 - (int)(key & 0xFFFFFFFFULL);
      float4 bb = bx[orig];  // original cxcywh
      v0 = bb.x; v1 = bb.y; v2 = bb.z; v3 = bb.w;
      v4 = __uint_as_float((unsigned int)(key >> 32));
    }
    float* o = out + ((size_t)b * MAXDET + tid) * 5;
    o[0] = v0; o[1] = v1; o[2] = v2; o[3] = v3; o[4] = v4;
  }
  if (tid == 0) out[(size_t)B * MAXDET * 5 + b] = (float)nk;
}

extern "C" void kernel_launch(void* const* d_in, const int* in_sizes, int n_in,
                              void* d_out, int out_size, void* d_ws, size_t ws_size,
                              hipStream_t stream) {
  const float* boxes = (const float*)d_in[0];
  const float* scores = (const float*)d_in[1];
  float* out = (float*)d_out;
  (void)d_ws; (void)ws_size; (void)n_in;
  const int B = out_size / (MAXDET * 5 + 1);  // [B,100,5] + [B]
  postproc_kernel<<<B, NT, 0, stream>>>(boxes, scores, out, B);
}

// Round 2
// 33.046 us; speedup vs baseline: 7.8879x; 7.8879x over previous
//
#include <hip/hip_runtime.h>

#define NT 512
#define NBOX 4096
#define MAXDET 100
#define KSEL 192      // target top-K selection size (needs >= 100 + suppressed margin)
#define CAP 512       // candidate array capacity
#define HBINS 2048    // histogram bins over score bits [31:20] (covers all positive floats)

typedef unsigned long long u64;
typedef unsigned int u32;

__device__ __forceinline__ float iou_xyxy(float4 a, float4 c) {
  float aa = fmaxf(a.z - a.x, 0.f) * fmaxf(a.w - a.y, 0.f);
  float ca = fmaxf(c.z - c.x, 0.f) * fmaxf(c.w - c.y, 0.f);
  float w = fmaxf(fminf(a.z, c.z) - fmaxf(a.x, c.x), 0.f);
  float h = fmaxf(fminf(a.w, c.w) - fmaxf(a.y, c.y), 0.f);
  float inter = w * h;
  return inter / fmaxf(aa + ca - inter, 1e-9f);
}

// Chunked greedy NMS over a sorted (descending) key prefix.
// keys: LDS, key = (score_bits<<32) | (NBOX-1-n). Appends kept entries
// (capped at MAXDET) to keptkey/keptbox; *p_kept updated. All threads enter.
__device__ void run_nms(const u64* keys, int len, const float4* __restrict__ bx,
                        float4* chbox, u64* srow, u64* keptkey, float4* keptbox,
                        u64* crossMask, int* p_kept, int tid) {
  for (int base = 0; base < len; base += 64) {
    if (*p_kept >= MAXDET) break;  // uniform (read after barrier)
    int L = min(64, len - base);
    // ---- stage chunk: keys -> xyxy boxes in LDS ----
    if (tid < 64) {
      if (tid == 0) *crossMask = 0ull;
      float4 bb = make_float4(0.f, 0.f, 0.f, 0.f);
      if (tid < L) {
        u64 k = keys[base + tid];
        int orig = NBOX - 1 - (int)(k & 0xFFFFFFFFull);
        float4 c = bx[orig];
        bb = make_float4(c.x - 0.5f * c.z, c.y - 0.5f * c.w,
                         c.x + 0.5f * c.z, c.y + 0.5f * c.w);
      }
      chbox[tid] = bb;
      srow[tid] = 0ull;
    }
    __syncthreads();
    int kept0 = *p_kept;
    // ---- parallel pair tests: 512 threads = 64 boxes x 8 slices ----
    {
      int i = tid & 63;
      int slice = tid >> 6;
      if (i < L) {
        float4 a = chbox[i];
        bool hit = false;
        for (int k0 = slice; k0 < kept0 && !hit; k0 += 8)
          if (iou_xyxy(a, keptbox[k0]) > 0.7f) hit = true;
        if (hit) atomicOr(crossMask, 1ull << i);
        u64 bits = 0ull;
        for (int j = i + 1 + slice; j < L; j += 8)
          if (iou_xyxy(a, chbox[j]) > 0.7f) bits |= 1ull << j;
        if (bits) atomicOr(&srow[i], bits);
      }
    }
    __syncthreads();
    // ---- wave-parallel greedy scan (wave 0 only) ----
    if (tid < 64) {
      u64 removed = *crossMask;
      if (L < 64) removed |= ~((1ull << L) - 1ull);
      u64 myrow = srow[tid];
      u64 keepm = 0ull;
      for (int ii = 0; ii < L; ++ii) {
        u64 row = __shfl(myrow, ii);  // uniform loop, all 64 lanes active
        if (!((removed >> ii) & 1ull)) {
          keepm |= 1ull << ii;
          removed |= row;
        }
      }
      if ((keepm >> tid) & 1ull) {
        int pos = kept0 + __popcll(keepm & ((1ull << tid) - 1ull));
        if (pos < MAXDET) {
          keptkey[pos] = keys[base + tid];
          keptbox[pos] = chbox[tid];
        }
      }
      if (tid == 0) *p_kept = min(MAXDET, kept0 + __popcll(keepm));
    }
    __syncthreads();
  }
}

__global__ __launch_bounds__(NT) void postproc_kernel(
    const float* __restrict__ boxes,   // [B, NBOX, 4] cxcywh
    const float* __restrict__ scores,  // [B, NBOX]
    float* __restrict__ out,           // [B*MAXDET*5] packed, then [B] num
    int B) {
  const int b = blockIdx.x;
  const int tid = threadIdx.x;

  __shared__ u64 skey[NBOX];          // 32KB (fallback sort; head reused as scan scratch)
  __shared__ u32 hist[HBINS];         // 8KB
  __shared__ u64 cand[CAP];           // 4KB
  __shared__ float4 chbox[64];
  __shared__ u64 srow[64];
  __shared__ float4 keptbox[MAXDET];
  __shared__ u64 keptkey[MAXDET];
  __shared__ u64 crossMask;
  __shared__ int s_M, s_C, s_kept, s_B, s_ovf;

  const float* sc = scores + (size_t)b * NBOX;
  const float4* bx = (const float4*)boxes + (size_t)b * NBOX;

  if (tid == 0) { s_M = 0; s_C = 0; s_kept = 0; s_B = 0; s_ovf = 0; }
  for (int h = tid; h < HBINS; h += NT) hist[h] = 0u;
  __syncthreads();

  // ---- Phase 1: score histogram + valid count; warm boxes into L2 ----
  int cnt = 0;
  for (int n = tid; n < NBOX; n += NT) {
    float s = sc[n];
    float4 bb = bx[n];                      // L2 warm for later scattered reads
    asm volatile("" ::"v"(bb.x), "v"(bb.z));
    if (s > 0.5f) {
      atomicAdd(&hist[__float_as_uint(s) >> 20], 1u);
      ++cnt;
    }
  }
  atomicAdd(&s_M, cnt);
  __syncthreads();
  const int M = s_M;

  // ---- Phase 2: bucket threshold for exact top-KSEL (only if M > CAP) ----
  int thrB = 0;
  if (M > CAP) {
    int* partial = (int*)skey;  // scratch overlay, rebuilt later if fallback
    int* sufx = partial + NT;
    int ps = 0;
#pragma unroll
    for (int q = 0; q < 4; ++q) ps += (int)hist[tid * 4 + q];
    partial[tid] = ps;
    __syncthreads();
    if (tid < 64) {  // wave 0: suffix sums over 512 partials, top-down
      int carry = 0;
      for (int r = 7; r >= 0; --r) {
        int v = partial[r * 64 + tid];
        for (int d = 1; d < 64; d <<= 1) {
          int o = __shfl_down(v, d);
          if (tid + d < 64) v += o;
        }
        sufx[r * 64 + tid] = v + carry;
        carry += __shfl(v, 0);
      }
    }
    __syncthreads();
    int above = sufx[tid] - partial[tid];  // count strictly above my 4 buckets
    if (above < KSEL && sufx[tid] >= KSEL) {  // unique crossing thread
      int running = above;
      for (int bk = 3; bk >= 0; --bk) {
        running += (int)hist[tid * 4 + bk];
        if (running >= KSEL) { s_B = tid * 4 + bk; break; }
      }
    }
    __syncthreads();
    thrB = s_B;
  }

  // ---- Phase 3: compact candidates (exact top prefix by score bits) ----
  for (int n = tid; n < NBOX; n += NT) {
    float s = sc[n];
    if (s > 0.5f) {
      u32 sb = __float_as_uint(s);
      if (M <= CAP || (int)(sb >> 20) >= thrB) {
        int pos = atomicAdd(&s_C, 1);
        if (pos < CAP)
          cand[pos] = ((u64)sb << 32) | (u64)(u32)(NBOX - 1 - n);
        else
          s_ovf = 1;
      }
    }
  }
  __syncthreads();
  const int C = min(s_C, CAP);
  const bool ovf = (s_ovf != 0);

  // ---- Phase 4: sort candidates (256 or 512 bitonic) + NMS ----
  if (!ovf && C > 0) {
    const int S = (C <= 256) ? 256 : CAP;
    for (int t2 = tid; t2 < S; t2 += NT)
      if (t2 >= C) cand[t2] = 0ull;  // pads sort to the end (descending)
    __syncthreads();
    for (int k = 2; k <= S; k <<= 1)
      for (int j = k >> 1; j > 0; j >>= 1) {
        if (tid < S) {
          int t = tid, ixj = t ^ j;
          if (ixj > t) {
            u64 a = cand[t], c2 = cand[ixj];
            bool up = (t & k) != 0;
            if (up ? (a > c2) : (a < c2)) { cand[t] = c2; cand[ixj] = a; }
          }
        }
        __syncthreads();
      }
    run_nms(cand, C, bx, chbox, srow, keptkey, keptbox, &crossMask, &s_kept, tid);
  }

  // ---- Phase 5: fully-general fallback (never taken on this input) ----
  const bool need_full = ovf || (s_kept < MAXDET && C < M);
  if (need_full) {
    if (tid == 0) s_kept = 0;
    for (int n = tid; n < NBOX; n += NT) {
      float s = sc[n];
      u64 key = (u64)(u32)(NBOX - 1 - n);
      if (s > 0.5f) key |= ((u64)__float_as_uint(s)) << 32;
      skey[n] = key;
    }
    __syncthreads();
    for (int k = 2; k <= NBOX; k <<= 1)
      for (int j = k >> 1; j > 0; j >>= 1) {
        for (int t = tid; t < NBOX; t += NT) {
          int ixj = t ^ j;
          if (ixj > t) {
            u64 a = skey[t], c2 = skey[ixj];
            bool up = (t & k) != 0;
            if (up ? (a > c2) : (a < c2)) { skey[t] = c2; skey[ixj] = a; }
          }
        }
        __syncthreads();
      }
    run_nms(skey, M, bx, chbox, srow, keptkey, keptbox, &crossMask, &s_kept, tid);
  }

  // ---- Phase 6: outputs ----
  const int nk = s_kept;
  if (tid < MAXDET) {
    float v0 = 0.f, v1 = 0.f, v2 = 0.f, v3 = 0.f, v4 = 0.f;
    if (tid < nk) {
      u64 key = keptkey[tid];
      int orig = NBOX - 1 - (int)(key & 0xFFFFFFFFull);
      float4 bb = bx[orig];  // original cxcywh
      v0 = bb.x; v1 = bb.y; v2 = bb.z; v3 = bb.w;
      v4 = __uint_as_float((u32)(key >> 32));
    }
    float* o = out + ((size_t)b * MAXDET + tid) * 5;
    o[0] = v0; o[1] = v1; o[2] = v2; o[3] = v3; o[4] = v4;
  }
  if (tid == 0) out[(size_t)B * MAXDET * 5 + b] = (float)nk;
}

extern "C" void kernel_launch(void* const* d_in, const int* in_sizes, int n_in,
                              void* d_out, int out_size, void* d_ws, size_t ws_size,
                              hipStream_t stream) {
  const float* boxes = (const float*)d_in[0];
  const float* scores = (const float*)d_in[1];
  float* out = (float*)d_out;
  (void)d_ws; (void)ws_size; (void)n_in;
  const int B = out_size / (MAXDET * 5 + 1);  // [B,100,5] + [B]
  postproc_kernel<<<B, NT, 0, stream>>>(boxes, scores, out, B);
}